// Round 5
// baseline (3542.895 us; speedup 1.0000x reference)
//
#include <hip/hip_runtime.h>
#include <hip/hip_bf16.h>
#include <stdint.h>

// CTRNN: B=64, T=1000, N_IN=128, N_REC=1024, N_OUT=64
// Persistent-group design, round 7 (halved broadcast redundancy):
//   grid = 128 WGs x 256 threads. group g = bid&3 (4 groups x 16 batches),
//   member m = bid>>2 (32 members, each owns 32 neurons and outputs 2m,2m+1).
//   Theory: rounds 4/6 showed flags (read-once) and tags (1.2x reads, one
//   fewer hop) land within 10% -> bandwidth-bound on the agent-scope h
//   broadcast at the LLC (~8MB/step = ~2.5TB/s sustained), not latency-bound.
//   Fix: double NSL to 32 -> half the consumer waves -> 4MB/step broadcast.
//   Exchange protocol is byte-identical to the passing round-6 kernel:
//   tag in bit31 of each packed h word (h=retanh>=0, sign free), producer
//   tags with ((t+1)>>1)&1 and just stores; consumer per-chunk retry with
//   s_sleep backoff; period-4 slot/phase disambiguation; hbuf poisoned 0xFF.
//   LDS: weff 64KB (swizzled) + wahxs 8KB + wyhs 4KB + red 12KB = 88KB.

#define B_    64
#define T_    1000
#define NIN   128
#define NREC  1024
#define NOUT  64
#define GROUPS  4
#define MEMBERS 32
#define BPG   16   // batches per group
#define NSL   32   // n-slice per member (2 MFMA row-tiles)

#define DT    0.1f

typedef short  bf16x8 __attribute__((ext_vector_type(8)));
typedef float  f32x4  __attribute__((ext_vector_type(4)));

#define SCOPE __HIP_MEMORY_SCOPE_AGENT

// ws layout
#define XB_OFF     0
#define XB_BYTES   (B_ * T_ * NIN * 2)                      // 16,384,000 (16B aligned)
#define HBUF_OFF   (XB_OFF + XB_BYTES)
#define HBUF_BYTES (GROUPS * 2 * BPG * NREC * 2)            // 262,144

#define TAGMASK 0x8000000080000000ull

union U16B { unsigned long long q[2]; bf16x8 s; };

__device__ __forceinline__ unsigned short f2bf(float f) {
    unsigned u = __float_as_uint(f);
    unsigned r = u + 0x7fffu + ((u >> 16) & 1u);
    return (unsigned short)(r >> 16);
}
__device__ __forceinline__ unsigned pack2(float lo, float hi) {
    return (unsigned)f2bf(lo) | ((unsigned)f2bf(hi) << 16);
}

__global__ void cast_x_kernel(const float* __restrict__ x, unsigned short* __restrict__ xb, int n4) {
    int i = blockIdx.x * blockDim.x + threadIdx.x;
    int stride = gridDim.x * blockDim.x;
    for (; i < n4; i += stride) {
        float4 v = ((const float4*)x)[i];
        unsigned lo = pack2(v.x, v.y);
        unsigned hi = pack2(v.z, v.w);
        ((uint2*)xb)[i] = make_uint2(lo, hi);
    }
}

__global__ __launch_bounds__(256, 1)
void rnn_main(const float* __restrict__ Wahx, const float* __restrict__ Wahh,
              const float* __restrict__ Wyh,  const float* __restrict__ bah,
              const float* __restrict__ by,   const float* __restrict__ ah0,
              const float* __restrict__ mask,
              const unsigned short* __restrict__ xb,
              unsigned short* __restrict__ hbuf,
              float* __restrict__ y)
{
    __shared__ unsigned short weff[NSL * NREC];   // 64 KB, swizzled rows
    __shared__ unsigned short wahxs[NSL * NIN];   // 8 KB, swizzled rows
    __shared__ unsigned short wyhs[2 * NREC];     // 4 KB, rows o=2m, 2m+1
    __shared__ float red[4][3][64][4];            // 12 KB: [wave][tile0/tile1/y][lane][reg]

    const int tid  = threadIdx.x;
    const int w    = tid >> 6;        // wave 0..3 (K-range w*256..)
    const int lane = tid & 63;
    const int bid  = blockIdx.x;
    const int g    = bid & 3;         // group
    const int m    = bid >> 2;        // member 0..31

    // ---- init: build LDS slabs ----
    for (int cc = 0; cc < 16; ++cc) {
        int cid = cc * 256 + tid;           // 4096 chunks of 8
        int rl = cid >> 7;                  // local row 0..31
        int k  = (cid & 127) * 8;
        const float* wr = Wahh + (m * NSL + rl) * NREC + k;
        const float* mr = mask + (m * NSL + rl) * NREC + k;
        float4 a0 = *(const float4*)wr;     float4 a1 = *(const float4*)(wr + 4);
        float4 m0 = *(const float4*)mr;     float4 m1 = *(const float4*)(mr + 4);
        uint4 pk;
        pk.x = pack2(fabsf(a0.x) * m0.x, fabsf(a0.y) * m0.y);
        pk.y = pack2(fabsf(a0.z) * m0.z, fabsf(a0.w) * m0.w);
        pk.z = pack2(fabsf(a1.x) * m1.x, fabsf(a1.y) * m1.y);
        pk.w = pack2(fabsf(a1.z) * m1.z, fabsf(a1.w) * m1.w);
        int byte = (rl * 2048 + k * 2) ^ ((rl & 7) << 4);
        *(uint4*)((char*)weff + byte) = pk;
    }
    for (int cc = 0; cc < 2; ++cc) {
        int cid = cc * 256 + tid;           // 512 chunks of 8
        int rl = cid >> 4;                  // local row 0..31
        int k  = (cid & 15) * 8;
        const float* wr = Wahx + (m * NSL + rl) * NIN + k;
        float4 a0 = *(const float4*)wr;  float4 a1 = *(const float4*)(wr + 4);
        uint4 pk;
        pk.x = pack2(a0.x, a0.y); pk.y = pack2(a0.z, a0.w);
        pk.z = pack2(a1.x, a1.y); pk.w = pack2(a1.z, a1.w);
        int byte = (rl * 256 + k * 2) ^ ((rl & 7) << 4);
        *(uint4*)((char*)wahxs + byte) = pk;
    }
    {
        int row = tid >> 7;                 // 0..1 (outputs 2m, 2m+1)
        int k   = (tid & 127) * 8;
        const float* wr = Wyh + (2 * m + row) * NREC + k;
        float4 a0 = *(const float4*)wr;  float4 a1 = *(const float4*)(wr + 4);
        uint4 pk;
        pk.x = pack2(a0.x, a0.y); pk.y = pack2(a0.z, a0.w);
        pk.z = pack2(a1.x, a1.y); pk.w = pack2(a1.z, a1.w);
        *(uint4*)((char*)wyhs + (row * 1024 + k) * 2) = pk;
    }

    // per-thread state: (b_loc, nl), two neurons per thread (tile 0 and 1)
    const int b_loc = tid >> 4;
    const int nl    = tid & 15;
    const int n_g0  = m * NSL + nl;        // tile-0 neuron
    const int n_g1  = n_g0 + 16;           // tile-1 neuron
    float ahv0 = ah0[n_g0], ahv1 = ah0[n_g1];
    float bahv0 = bah[n_g0], bahv1 = bah[n_g1];
    float byv0 = by[2 * m], byv1 = by[2 * m + 1];

    // h(0) = retanh(ah0) -> hbuf slot 0, tag 0 (natural sign bits)
    {
        float t0 = tanhf(ahv0);  float h0 = t0 > 0.f ? t0 : 0.f;
        float t1 = tanhf(ahv1);  float h1 = t1 > 0.f ? t1 : 0.f;
        unsigned hb0 = f2bf(h0), hb1 = f2bf(h1);
        unsigned nb0 = __shfl_down(hb0, 1), nb1 = __shfl_down(hb1, 1);
        if ((nl & 1) == 0) {
            int e0 = ((g * 2 + 0) * BPG + b_loc) * NREC + n_g0;
            int e1 = ((g * 2 + 0) * BPG + b_loc) * NREC + n_g1;
            __hip_atomic_store((unsigned*)hbuf + (e0 >> 1), hb0 | (nb0 << 16), __ATOMIC_RELAXED, SCOPE);
            __hip_atomic_store((unsigned*)hbuf + (e1 >> 1), hb1 | (nb1 << 16), __ATOMIC_RELAXED, SCOPE);
        }
    }
    __syncthreads();   // LDS slabs ready before use

    const int bcol = lane & 15;          // batch col for MFMA, also A row
    const int khi  = (lane >> 4) * 8;    // per-lane k offset within 32-chunk

    for (int t = 0; t <= T_; ++t) {
        // ---- prefetch x fragment (independent of h(t)) ----
        bf16x8 xf, axf0, axf1;
        if (t < T_) {
            int i = w * 32 + khi;
            xf = *(const bf16x8*)(xb + ((size_t)(g * BPG + bcol) * T_ + t) * NIN + i);
            int by0 = (bcol * 256 + i * 2) ^ ((bcol & 7) << 4);
            int by1 = ((bcol + 16) * 256 + i * 2) ^ ((bcol & 7) << 4);
            axf0 = *(const bf16x8*)((const char*)wahxs + by0);
            axf1 = *(const bf16x8*)((const char*)wahxs + by1);
        }

        // ---- poll-load h(t): per-chunk retry, tags self-certify ----
        const int slot = t & 1;
        const unsigned long long want = ((t >> 1) & 1) ? TAGMASK : 0ull;
        const unsigned long long* hq =
            (const unsigned long long*)(hbuf + ((g * 2 + slot) * BPG + bcol) * NREC);

        U16B u[8];
        unsigned pend = 0xFFu;           // per-lane pending chunk mask
        for (;;) {
            #pragma unroll
            for (int c = 0; c < 8; ++c) {
                if (pend & (1u << c)) {
                    int k = w * 256 + c * 32 + khi;
                    u[c].q[0] = __hip_atomic_load(hq + (k >> 2),     __ATOMIC_RELAXED, SCOPE);
                    u[c].q[1] = __hip_atomic_load(hq + (k >> 2) + 1, __ATOMIC_RELAXED, SCOPE);
                }
            }
            unsigned np = 0u;
            #pragma unroll
            for (int c = 0; c < 8; ++c) {
                if (pend & (1u << c)) {
                    unsigned long long d = ((u[c].q[0] ^ want) | (u[c].q[1] ^ want)) & TAGMASK;
                    np |= d ? (1u << c) : 0u;
                }
            }
            pend = np;
            if (!__any(pend != 0u)) break;
            __builtin_amdgcn_s_sleep(1);   // ~64cy backoff: don't hammer the LLC
        }
        bf16x8 bfrag[8];
        #pragma unroll
        for (int c = 0; c < 8; ++c) {
            u[c].q[0] &= ~TAGMASK;      // clear tags (real sign bits are 0)
            u[c].q[1] &= ~TAGMASK;
            bfrag[c] = u[c].s;
        }

        f32x4 acc0 = {0.f, 0.f, 0.f, 0.f};
        f32x4 acc1 = {0.f, 0.f, 0.f, 0.f};
        if (t < T_) {
            // per tile: two independent accumulator chains
            f32x4 p00 = {0.f, 0.f, 0.f, 0.f}, p01 = {0.f, 0.f, 0.f, 0.f};
            f32x4 p10 = {0.f, 0.f, 0.f, 0.f}, p11 = {0.f, 0.f, 0.f, 0.f};
            p00 = __builtin_amdgcn_mfma_f32_16x16x32_bf16(axf0, xf, p00, 0, 0, 0);
            p10 = __builtin_amdgcn_mfma_f32_16x16x32_bf16(axf1, xf, p10, 0, 0, 0);
            #pragma unroll
            for (int c = 0; c < 4; ++c) {
                int k = w * 256 + c * 32 + khi;
                int by0 = (bcol * 2048 + k * 2) ^ ((bcol & 7) << 4);
                int by1 = ((bcol + 16) * 2048 + k * 2) ^ ((bcol & 7) << 4);
                bf16x8 af0 = *(const bf16x8*)((const char*)weff + by0);
                bf16x8 af1 = *(const bf16x8*)((const char*)weff + by1);
                p00 = __builtin_amdgcn_mfma_f32_16x16x32_bf16(af0, bfrag[c], p00, 0, 0, 0);
                p10 = __builtin_amdgcn_mfma_f32_16x16x32_bf16(af1, bfrag[c], p10, 0, 0, 0);
            }
            #pragma unroll
            for (int c = 4; c < 8; ++c) {
                int k = w * 256 + c * 32 + khi;
                int by0 = (bcol * 2048 + k * 2) ^ ((bcol & 7) << 4);
                int by1 = ((bcol + 16) * 2048 + k * 2) ^ ((bcol & 7) << 4);
                bf16x8 af0 = *(const bf16x8*)((const char*)weff + by0);
                bf16x8 af1 = *(const bf16x8*)((const char*)weff + by1);
                p01 = __builtin_amdgcn_mfma_f32_16x16x32_bf16(af0, bfrag[c], p01, 0, 0, 0);
                p11 = __builtin_amdgcn_mfma_f32_16x16x32_bf16(af1, bfrag[c], p11, 0, 0, 0);
            }
            acc0 = p00 + p01;
            acc1 = p10 + p11;
        }

        *(f32x4*)&red[w][0][lane][0] = acc0;
        *(f32x4*)&red[w][1][lane][0] = acc1;
        __syncthreads();

        if (t < T_) {
            // D mapping: col = lane&15 (=batch), row = (lane>>4)*4 + reg (=n-local)
            int src = ((nl >> 2) << 4) | b_loc;
            int reg = nl & 3;
            float r0 = red[0][0][src][reg] + red[1][0][src][reg]
                     + red[2][0][src][reg] + red[3][0][src][reg];
            float r1 = red[0][1][src][reg] + red[1][1][src][reg]
                     + red[2][1][src][reg] + red[3][1][src][reg];
            ahv0 = 0.9f * ahv0 + DT * (r0 + bahv0);
            ahv1 = 0.9f * ahv1 + DT * (r1 + bahv1);
            float t0 = tanhf(ahv0);  float h0 = t0 > 0.f ? t0 : 0.f;
            float t1 = tanhf(ahv1);  float h1 = t1 > 0.f ? t1 : 0.f;
            unsigned hb0 = f2bf(h0), hb1 = f2bf(h1);
            unsigned nb0 = __shfl_down(hb0, 1), nb1 = __shfl_down(hb1, 1);
            if ((nl & 1) == 0) {
                unsigned tagw = (unsigned)(((t + 1) >> 1) & 1) << 31;
                int e0 = ((g * 2 + (slot ^ 1)) * BPG + b_loc) * NREC + n_g0;
                int e1 = ((g * 2 + (slot ^ 1)) * BPG + b_loc) * NREC + n_g1;
                __hip_atomic_store((unsigned*)hbuf + (e0 >> 1),
                                   hb0 | (nb0 << 16) | tagw, __ATOMIC_RELAXED, SCOPE);
                __hip_atomic_store((unsigned*)hbuf + (e1 >> 1),
                                   hb1 | (nb1 << 16) | tagw, __ATOMIC_RELAXED, SCOPE);
            }
            // no ack, no flag: each word self-announces via its tag
        }

        // ---- y for output step t-1 (off the critical inter-WG chain) ----
        if (t >= 1) {
            f32x4 accy = {0.f, 0.f, 0.f, 0.f};
            #pragma unroll
            for (int c = 0; c < 8; ++c) {
                int k = w * 256 + c * 32 + khi;
                bf16x8 yaf = {0, 0, 0, 0, 0, 0, 0, 0};
                if (bcol < 2)
                    yaf = *(const bf16x8*)((const char*)wyhs + (bcol * 1024 + k) * 2);
                accy = __builtin_amdgcn_mfma_f32_16x16x32_bf16(yaf, bfrag[c], accy, 0, 0, 0);
            }
            *(f32x4*)&red[w][2][lane][0] = accy;
            __syncthreads();
            if (tid < BPG) {
                float yv0 = red[0][2][tid][0] + red[1][2][tid][0]
                          + red[2][2][tid][0] + red[3][2][tid][0] + byv0;
                float yv1 = red[0][2][tid][1] + red[1][2][tid][1]
                          + red[2][2][tid][1] + red[3][2][tid][1] + byv1;
                union { float f[2]; double d; } uu;
                uu.f[0] = yv0; uu.f[1] = yv1;
                __builtin_nontemporal_store(uu.d,
                    (double*)&y[((size_t)(g * BPG + tid) * T_ + (t - 1)) * NOUT + 2 * m]);
            }
        } else {
            // t==0 has no y-phase barrier; order red[][0..1] reads before t=1 writes.
            __syncthreads();
        }
    }
}

extern "C" void kernel_launch(void* const* d_in, const int* in_sizes, int n_in,
                              void* d_out, int out_size, void* d_ws, size_t ws_size,
                              hipStream_t stream) {
    const float* x    = (const float*)d_in[0];
    const float* Wahx = (const float*)d_in[1];
    const float* Wahh = (const float*)d_in[2];
    const float* Wyh  = (const float*)d_in[3];
    const float* bah  = (const float*)d_in[4];
    const float* by   = (const float*)d_in[5];
    const float* ah0  = (const float*)d_in[6];
    const float* mask = (const float*)d_in[7];
    float* y = (float*)d_out;
    char* ws = (char*)d_ws;
    unsigned short* xb   = (unsigned short*)(ws + XB_OFF);
    unsigned short* hbuf = (unsigned short*)(ws + HBUF_OFF);

    (void)in_sizes; (void)n_in; (void)out_size; (void)ws_size;

    // poison hbuf: all tag bits = 1, so phase-0 consumers (t=0,1) cannot
    // false-accept before the first writes land.
    hipMemsetAsync(hbuf, 0xFF, HBUF_BYTES, stream);
    cast_x_kernel<<<dim3(2048), dim3(256), 0, stream>>>(x, xb, (B_ * T_ * NIN) / 4);
    rnn_main<<<dim3(GROUPS * MEMBERS), dim3(256), 0, stream>>>(
        Wahx, Wahh, Wyh, bah, by, ah0, mask, xb, hbuf, y);
}